// Round 1
// baseline (221.916 us; speedup 1.0000x reference)
//
#include <hip/hip_runtime.h>
#include <math.h>

// Problem constants (N,C,H,W,D) = (64, 3, 256, 256, 512)
#define N_B 64
#define C_CH 3
#define H_IMG 256
#define W_IMG 256
#define D_FEAT 512

// d_out layout (flat fp32, return order):
//   out:           [0,            12582912)   (N,C,H,W)
//   grid:          [12582912,     20971520)   (N,H,W,2)
//   matrix:        [20971520,     20971904)   (N,2,3)
//   affine_params: [20971904,     20972160)   (N,4)
#define OUT_OFF_GRID   12582912
#define OUT_OFF_MATRIX 20971520
#define OUT_OFF_AFFINE 20971904

// ------------------------------------------------------------------
// Kernel 1: per-batch linear head -> affine matrix + level
// one block per batch, 256 threads reduce the 512-long dot products
// ------------------------------------------------------------------
__global__ void params_kernel(const float* __restrict__ features,
                              const float* __restrict__ lin_w,
                              const float* __restrict__ lin_b,
                              float* __restrict__ out_matrix,
                              float* __restrict__ out_affine,
                              float* __restrict__ ws_params)
{
    const int n = blockIdx.x;
    const int t = threadIdx.x;
    const float* f = features + n * D_FEAT;
    float f0 = f[t];
    float f1 = f[t + 256];
    float a0 = f0 * lin_w[0 * D_FEAT + t] + f1 * lin_w[0 * D_FEAT + t + 256];
    float a1 = f0 * lin_w[1 * D_FEAT + t] + f1 * lin_w[1 * D_FEAT + t + 256];
    float a2 = f0 * lin_w[2 * D_FEAT + t] + f1 * lin_w[2 * D_FEAT + t + 256];
    float a3 = f0 * lin_w[3 * D_FEAT + t] + f1 * lin_w[3 * D_FEAT + t + 256];

    __shared__ float red[4][256];
    red[0][t] = a0; red[1][t] = a1; red[2][t] = a2; red[3][t] = a3;
    __syncthreads();
    for (int s = 128; s > 0; s >>= 1) {
        if (t < s) {
            red[0][t] += red[0][t + s];
            red[1][t] += red[1][t + s];
            red[2][t] += red[2][t + s];
            red[3][t] += red[3][t + s];
        }
        __syncthreads();
    }
    if (t == 0) {
        float p0 = red[0][0] + lin_b[0];
        float p1 = red[1][0] + lin_b[1];
        float p2 = red[2][0] + lin_b[2];
        float p3 = red[3][0] + lin_b[3];
        float rot   = tanhf(p0) * 3.14159265358979323846f;
        float scale = expf(p1);
        float c = cosf(rot), s = sinf(rot);
        float m00 = scale * c, m01 = -scale * s, m02 = p2;
        float m10 = scale * s, m11 =  scale * c, m12 = p3;
        out_matrix[n * 6 + 0] = m00;
        out_matrix[n * 6 + 1] = m01;
        out_matrix[n * 6 + 2] = m02;
        out_matrix[n * 6 + 3] = m10;
        out_matrix[n * 6 + 4] = m11;
        out_matrix[n * 6 + 5] = m12;
        out_affine[n * 4 + 0] = rot;
        out_affine[n * 4 + 1] = scale;
        out_affine[n * 4 + 2] = p2;
        out_affine[n * 4 + 3] = p3;
        // levels: for an affine grid, ||d coords/dw|| = ||d coords/dh|| = scale exactly
        float lv = log2f(fmaxf(scale, 1.0f));
        lv = fminf(fmaxf(lv, 0.0f), 2.5f);   // MAX_NUM_LEVELS - 1 = 2.5
        ws_params[n * 8 + 0] = m00;
        ws_params[n * 8 + 1] = m01;
        ws_params[n * 8 + 2] = m02;
        ws_params[n * 8 + 3] = m10;
        ws_params[n * 8 + 4] = m11;
        ws_params[n * 8 + 5] = m12;
        ws_params[n * 8 + 6] = lv;
        ws_params[n * 8 + 7] = 0.0f;
    }
}

// ------------------------------------------------------------------
// Kernel 2: depthwise 4x4 binomial blur, reflect pad (1,2), stride 2
// ------------------------------------------------------------------
__global__ void down_kernel(const float* __restrict__ src, float* __restrict__ dst,
                            int Hs, int Ws, int Hd, int Wd, int total)
{
    int idx = blockIdx.x * blockDim.x + threadIdx.x;
    if (idx >= total) return;
    int j   = idx % Wd;
    int tmp = idx / Wd;
    int i   = tmp % Hd;
    int nc  = tmp / Hd;
    const float* s = src + (size_t)nc * Hs * Ws;
    const float k[4] = {0.125f, 0.375f, 0.375f, 0.125f};
    int qy[4], qx[4];
#pragma unroll
    for (int a = 0; a < 4; a++) {
        int q = 2 * i + a - 1;
        if (q < 0) q = -q;                 // reflect (no edge repeat)
        if (q >= Hs) q = 2 * Hs - 2 - q;
        qy[a] = q;
        int r = 2 * j + a - 1;
        if (r < 0) r = -r;
        if (r >= Ws) r = 2 * Ws - 2 - r;
        qx[a] = r;
    }
    float acc = 0.0f;
#pragma unroll
    for (int a = 0; a < 4; a++) {
        const float* row = s + (size_t)qy[a] * Ws;
        float rsum = k[0] * row[qx[0]] + k[1] * row[qx[1]]
                   + k[2] * row[qx[2]] + k[3] * row[qx[3]];
        acc += k[a] * rsum;
    }
    dst[idx] = acc;
}

// ------------------------------------------------------------------
// Kernel 3: affine grid + mipmap bilinear warp
// ------------------------------------------------------------------
__device__ __forceinline__ void sample_level(const float* __restrict__ p, int n, int l,
                                             float X, float Y, float out[3])
{
    const int Wl = W_IMG >> l;
    const int Hl = H_IMG >> l;
    float x = (X + 1.0f) * (0.5f * (float)Wl) - 0.5f;
    float y = (Y + 1.0f) * (0.5f * (float)Hl) - 0.5f;
    float x0f = floorf(x), y0f = floorf(y);
    float tx = x - x0f, ty = y - y0f;
    int x0 = (int)x0f, y0 = (int)y0f;
    int x0i = min(max(x0,     0), Wl - 1);
    int x1i = min(max(x0 + 1, 0), Wl - 1);
    int y0i = min(max(y0,     0), Hl - 1);
    int y1i = min(max(y0 + 1, 0), Hl - 1);
    float w00 = (1.0f - tx) * (1.0f - ty);
    float w01 = tx * (1.0f - ty);
    float w10 = (1.0f - tx) * ty;
    float w11 = tx * ty;
    const float* base = p + (size_t)n * C_CH * Hl * Wl;
#pragma unroll
    for (int c = 0; c < C_CH; c++) {
        const float* pc = base + (size_t)c * Hl * Wl;
        out[c] = w00 * pc[y0i * Wl + x0i] + w01 * pc[y0i * Wl + x1i]
               + w10 * pc[y1i * Wl + x0i] + w11 * pc[y1i * Wl + x1i];
    }
}

__device__ __forceinline__ const float* lvl_ptr(int l, const float* img,
                                                const float* p1, const float* p2,
                                                const float* p3)
{
    return (l == 0) ? img : ((l == 1) ? p1 : ((l == 2) ? p2 : p3));
}

__global__ void warp_kernel(const float* __restrict__ img,
                            const float* __restrict__ pyr1,
                            const float* __restrict__ pyr2,
                            const float* __restrict__ pyr3,
                            const float* __restrict__ ws_params,
                            float* __restrict__ out,
                            float* __restrict__ gridOut)
{
    const int n   = blockIdx.y;
    const int pix = blockIdx.x * blockDim.x + threadIdx.x;   // 0..H*W-1
    const int h = pix >> 8;
    const int w = pix & 255;

    const float* P = ws_params + n * 8;
    float m00 = P[0], m01 = P[1], m02 = P[2];
    float m10 = P[3], m11 = P[4], m12 = P[5];
    float lv  = P[6];

    float gx = ((float)w + 0.5f) * (2.0f / (float)W_IMG) - 1.0f;
    float gy = ((float)h + 0.5f) * (2.0f / (float)H_IMG) - 1.0f;
    float X = m00 * gx + m01 * gy + m02;
    float Y = m10 * gx + m11 * gy + m12;

    // grid output (N,H,W,2) — coalesced float2 store
    float2* g2 = (float2*)gridOut;
    g2[(size_t)(n * H_IMG + h) * W_IMG + w] = make_float2(X, Y);

    int   l0   = (int)lv;          // lv in [0, 2.5] so trunc == floor
    float frac = lv - (float)l0;

    float c0[3];
    sample_level(lvl_ptr(l0, img, pyr1, pyr2, pyr3), n, l0, X, Y, c0);

    float r0, r1, r2;
    if (frac > 0.0f) {             // wave-uniform branch (one n per block)
        float c1[3];
        sample_level(lvl_ptr(l0 + 1, img, pyr1, pyr2, pyr3), n, l0 + 1, X, Y, c1);
        float w0 = 1.0f - frac;
        r0 = w0 * c0[0] + frac * c1[0];
        r1 = w0 * c0[1] + frac * c1[1];
        r2 = w0 * c0[2] + frac * c1[2];
    } else {
        r0 = c0[0]; r1 = c0[1]; r2 = c0[2];
    }

    size_t base = ((size_t)(n * C_CH + 0) * H_IMG + h) * W_IMG + w;
    out[base]                                = r0;
    out[base + (size_t)H_IMG * W_IMG]        = r1;
    out[base + (size_t)2 * H_IMG * W_IMG]    = r2;
}

// ------------------------------------------------------------------
extern "C" void kernel_launch(void* const* d_in, const int* in_sizes, int n_in,
                              void* d_out, int out_size, void* d_ws, size_t ws_size,
                              hipStream_t stream)
{
    const float* img      = (const float*)d_in[0];
    const float* features = (const float*)d_in[1];
    const float* lin_w    = (const float*)d_in[2];
    const float* lin_b    = (const float*)d_in[3];

    float* out        = (float*)d_out;
    float* gridOut    = out + OUT_OFF_GRID;
    float* out_matrix = out + OUT_OFF_MATRIX;
    float* out_affine = out + OUT_OFF_AFFINE;

    // workspace layout: params (1024 floats, 4 KB), then pyramid levels 1..3
    float* ws        = (float*)d_ws;
    float* ws_params = ws;
    float* pyr1 = ws + 1024;                       // 64*3*128*128 = 3145728 floats
    float* pyr2 = pyr1 + (size_t)N_B * C_CH * 128 * 128;  // 64*3*64*64
    float* pyr3 = pyr2 + (size_t)N_B * C_CH * 64 * 64;    // 64*3*32*32
    // total ws use: ~15.76 MB

    params_kernel<<<N_B, 256, 0, stream>>>(features, lin_w, lin_b,
                                           out_matrix, out_affine, ws_params);

    int t1 = N_B * C_CH * 128 * 128;
    down_kernel<<<(t1 + 255) / 256, 256, 0, stream>>>(img,  pyr1, 256, 256, 128, 128, t1);
    int t2 = N_B * C_CH * 64 * 64;
    down_kernel<<<(t2 + 255) / 256, 256, 0, stream>>>(pyr1, pyr2, 128, 128, 64, 64, t2);
    int t3 = N_B * C_CH * 32 * 32;
    down_kernel<<<(t3 + 255) / 256, 256, 0, stream>>>(pyr2, pyr3, 64, 64, 32, 32, t3);

    // grid: 256 blocks of 256 threads cover H*W per batch; blockIdx.y = n
    warp_kernel<<<dim3(H_IMG * W_IMG / 256, N_B), 256, 0, stream>>>(
        img, pyr1, pyr2, pyr3, ws_params, out, gridOut);
}

// Round 2
// 198.398 us; speedup vs baseline: 1.1185x; 1.1185x over previous
//
#include <hip/hip_runtime.h>
#include <math.h>

// Problem constants (N,C,H,W,D) = (64, 3, 256, 256, 512)
#define N_B 64
#define C_CH 3
#define H_IMG 256
#define W_IMG 256
#define D_FEAT 512

// d_out layout (flat fp32, return order):
//   out:           [0,            12582912)   (N,C,H,W)
//   grid:          [12582912,     20971520)   (N,H,W,2)
//   matrix:        [20971520,     20971904)   (N,2,3)
//   affine_params: [20971904,     20972160)   (N,4)
#define OUT_OFF_GRID   12582912
#define OUT_OFF_MATRIX 20971520
#define OUT_OFF_AFFINE 20971904

// ------------------------------------------------------------------
// Kernel 1: per-batch linear head -> affine matrix + level
// ------------------------------------------------------------------
__global__ void params_kernel(const float* __restrict__ features,
                              const float* __restrict__ lin_w,
                              const float* __restrict__ lin_b,
                              float* __restrict__ out_matrix,
                              float* __restrict__ out_affine,
                              float* __restrict__ ws_params)
{
    const int n = blockIdx.x;
    const int t = threadIdx.x;
    const float* f = features + n * D_FEAT;
    float f0 = f[t];
    float f1 = f[t + 256];
    float a0 = f0 * lin_w[0 * D_FEAT + t] + f1 * lin_w[0 * D_FEAT + t + 256];
    float a1 = f0 * lin_w[1 * D_FEAT + t] + f1 * lin_w[1 * D_FEAT + t + 256];
    float a2 = f0 * lin_w[2 * D_FEAT + t] + f1 * lin_w[2 * D_FEAT + t + 256];
    float a3 = f0 * lin_w[3 * D_FEAT + t] + f1 * lin_w[3 * D_FEAT + t + 256];

    __shared__ float red[4][256];
    red[0][t] = a0; red[1][t] = a1; red[2][t] = a2; red[3][t] = a3;
    __syncthreads();
    for (int s = 128; s > 0; s >>= 1) {
        if (t < s) {
            red[0][t] += red[0][t + s];
            red[1][t] += red[1][t + s];
            red[2][t] += red[2][t + s];
            red[3][t] += red[3][t + s];
        }
        __syncthreads();
    }
    if (t == 0) {
        float p0 = red[0][0] + lin_b[0];
        float p1 = red[1][0] + lin_b[1];
        float p2 = red[2][0] + lin_b[2];
        float p3 = red[3][0] + lin_b[3];
        float rot   = tanhf(p0) * 3.14159265358979323846f;
        float scale = expf(p1);
        float c = cosf(rot), s = sinf(rot);
        float m00 = scale * c, m01 = -scale * s, m02 = p2;
        float m10 = scale * s, m11 =  scale * c, m12 = p3;
        out_matrix[n * 6 + 0] = m00;
        out_matrix[n * 6 + 1] = m01;
        out_matrix[n * 6 + 2] = m02;
        out_matrix[n * 6 + 3] = m10;
        out_matrix[n * 6 + 4] = m11;
        out_matrix[n * 6 + 5] = m12;
        out_affine[n * 4 + 0] = rot;
        out_affine[n * 4 + 1] = scale;
        out_affine[n * 4 + 2] = p2;
        out_affine[n * 4 + 3] = p3;
        // affine grid => Jacobian norm is exactly `scale` in both directions
        float lv = log2f(fmaxf(scale, 1.0f));
        lv = fminf(fmaxf(lv, 0.0f), 2.5f);   // MAX_NUM_LEVELS - 1 = 2.5
        ws_params[n * 8 + 0] = m00;
        ws_params[n * 8 + 1] = m01;
        ws_params[n * 8 + 2] = m02;
        ws_params[n * 8 + 3] = m10;
        ws_params[n * 8 + 4] = m11;
        ws_params[n * 8 + 5] = m12;
        ws_params[n * 8 + 6] = lv;
        ws_params[n * 8 + 7] = 0.0f;
    }
}

// ------------------------------------------------------------------
// Kernel 2: depthwise 4x4 binomial blur, reflect pad (1,2), stride 2.
// Compile-time dims; each thread computes 2 adjacent outputs from
// one aligned float4 + 2 scalar loads per source row.
// ------------------------------------------------------------------
template<int Hs, int Ws>
__global__ void down_kernel(const float* __restrict__ src, float* __restrict__ dst)
{
    constexpr int Hd = Hs / 2, Wd = Ws / 2;
    constexpr int PAIRS = Wd / 2;          // output pairs per row

    const int idx = blockIdx.x * blockDim.x + threadIdx.x;  // grid sized exactly
    const int t   = idx & (PAIRS - 1);                      // pair index (pow2)
    const int i   = (idx / PAIRS) & (Hd - 1);               // output row (pow2)
    const int nc  = idx / (PAIRS * Hd);

    const float* __restrict__ s = src + (size_t)nc * Hs * Ws;

    // source rows 2i-1 .. 2i+2 with reflect (no edge repeat)
    int r[4];
#pragma unroll
    for (int a = 0; a < 4; a++) {
        int q = 2 * i + a - 1;
        if (q < 0) q = -q;
        if (q >= Hs) q = 2 * Hs - 2 - q;
        r[a] = q;
    }
    const int c4 = 4 * t;                                  // aligned float4 col base
    const int li = (t > 0)         ? c4 - 1 : 1;           // reflect col -1 -> 1
    const int ri = (t < PAIRS - 1) ? c4 + 4 : Ws - 2;      // reflect col Ws -> Ws-2

    const float k0 = 0.125f, k1 = 0.375f;
    const float kr[4] = {0.125f, 0.375f, 0.375f, 0.125f};

    float acc0 = 0.0f, acc1 = 0.0f;
#pragma unroll
    for (int a = 0; a < 4; a++) {
        const float* row = s + (size_t)r[a] * Ws;
        float4 v = *(const float4*)(row + c4);
        float L = row[li];
        float R = row[ri];
        // out j=2t   needs cols 4t-1..4t+2  = L, v.x, v.y, v.z
        // out j=2t+1 needs cols 4t+1..4t+4  = v.y, v.z, v.w, R
        float h0 = k0 * L   + k1 * v.x + k1 * v.y + k0 * v.z;
        float h1 = k0 * v.y + k1 * v.z + k1 * v.w + k0 * R;
        acc0 += kr[a] * h0;
        acc1 += kr[a] * h1;
    }
    float2* d2 = (float2*)(dst + (size_t)nc * Hd * Wd + (size_t)i * Wd);
    d2[t] = make_float2(acc0, acc1);
}

// ------------------------------------------------------------------
// Kernel 3: affine grid + mipmap bilinear warp, 32x8 pixel tiles
// ------------------------------------------------------------------
__device__ __forceinline__ void sample_level(const float* __restrict__ p, int n, int l,
                                             float X, float Y, float out[3])
{
    const int Wl = W_IMG >> l;
    const int Hl = H_IMG >> l;
    float x = (X + 1.0f) * (0.5f * (float)Wl) - 0.5f;
    float y = (Y + 1.0f) * (0.5f * (float)Hl) - 0.5f;
    float x0f = floorf(x), y0f = floorf(y);
    float tx = x - x0f, ty = y - y0f;
    int x0 = (int)x0f, y0 = (int)y0f;
    int x0i = min(max(x0,     0), Wl - 1);
    int x1i = min(max(x0 + 1, 0), Wl - 1);
    int y0i = min(max(y0,     0), Hl - 1);
    int y1i = min(max(y0 + 1, 0), Hl - 1);
    float w00 = (1.0f - tx) * (1.0f - ty);
    float w01 = tx * (1.0f - ty);
    float w10 = (1.0f - tx) * ty;
    float w11 = tx * ty;
    const float* base = p + (size_t)n * C_CH * Hl * Wl;
#pragma unroll
    for (int c = 0; c < C_CH; c++) {
        const float* pc = base + (size_t)c * Hl * Wl;
        out[c] = w00 * pc[y0i * Wl + x0i] + w01 * pc[y0i * Wl + x1i]
               + w10 * pc[y1i * Wl + x0i] + w11 * pc[y1i * Wl + x1i];
    }
}

__device__ __forceinline__ const float* lvl_ptr(int l, const float* img,
                                                const float* p1, const float* p2,
                                                const float* p3)
{
    return (l == 0) ? img : ((l == 1) ? p1 : ((l == 2) ? p2 : p3));
}

__global__ void warp_kernel(const float* __restrict__ img,
                            const float* __restrict__ pyr1,
                            const float* __restrict__ pyr2,
                            const float* __restrict__ pyr3,
                            const float* __restrict__ ws_params,
                            float* __restrict__ out,
                            float* __restrict__ gridOut)
{
    const int n = blockIdx.y;
    // 32x8 pixel tile per block: 8 tiles across, 32 tiles down
    const int tile = blockIdx.x;
    const int w = ((tile & 7) << 5) + (threadIdx.x & 31);
    const int h = ((tile >> 3) << 3) + (threadIdx.x >> 5);

    const float* P = ws_params + n * 8;
    float m00 = P[0], m01 = P[1], m02 = P[2];
    float m10 = P[3], m11 = P[4], m12 = P[5];
    float lv  = P[6];

    float gx = ((float)w + 0.5f) * (2.0f / (float)W_IMG) - 1.0f;
    float gy = ((float)h + 0.5f) * (2.0f / (float)H_IMG) - 1.0f;
    float X = m00 * gx + m01 * gy + m02;
    float Y = m10 * gx + m11 * gy + m12;

    // grid output (N,H,W,2)
    float2* g2 = (float2*)gridOut;
    g2[(size_t)(n * H_IMG + h) * W_IMG + w] = make_float2(X, Y);

    int   l0   = (int)lv;          // lv in [0, 2.5]: trunc == floor
    float frac = lv - (float)l0;

    float c0[3];
    sample_level(lvl_ptr(l0, img, pyr1, pyr2, pyr3), n, l0, X, Y, c0);

    float r0, r1, r2;
    if (frac > 0.0f) {             // wave-uniform (one n per block)
        float c1[3];
        sample_level(lvl_ptr(l0 + 1, img, pyr1, pyr2, pyr3), n, l0 + 1, X, Y, c1);
        float w0 = 1.0f - frac;
        r0 = w0 * c0[0] + frac * c1[0];
        r1 = w0 * c0[1] + frac * c1[1];
        r2 = w0 * c0[2] + frac * c1[2];
    } else {
        r0 = c0[0]; r1 = c0[1]; r2 = c0[2];
    }

    size_t base = ((size_t)(n * C_CH + 0) * H_IMG + h) * W_IMG + w;
    out[base]                             = r0;
    out[base + (size_t)H_IMG * W_IMG]     = r1;
    out[base + (size_t)2 * H_IMG * W_IMG] = r2;
}

// ------------------------------------------------------------------
extern "C" void kernel_launch(void* const* d_in, const int* in_sizes, int n_in,
                              void* d_out, int out_size, void* d_ws, size_t ws_size,
                              hipStream_t stream)
{
    const float* img      = (const float*)d_in[0];
    const float* features = (const float*)d_in[1];
    const float* lin_w    = (const float*)d_in[2];
    const float* lin_b    = (const float*)d_in[3];

    float* out        = (float*)d_out;
    float* gridOut    = out + OUT_OFF_GRID;
    float* out_matrix = out + OUT_OFF_MATRIX;
    float* out_affine = out + OUT_OFF_AFFINE;

    float* ws        = (float*)d_ws;
    float* ws_params = ws;
    float* pyr1 = ws + 1024;                              // 64*3*128*128
    float* pyr2 = pyr1 + (size_t)N_B * C_CH * 128 * 128;  // 64*3*64*64
    float* pyr3 = pyr2 + (size_t)N_B * C_CH * 64 * 64;    // 64*3*32*32

    params_kernel<<<N_B, 256, 0, stream>>>(features, lin_w, lin_b,
                                           out_matrix, out_affine, ws_params);

    // threads = NC * Hd * Wd/2 ; all divide exactly by 256
    int t1 = N_B * C_CH * 128 * 64;
    down_kernel<256, 256><<<t1 / 256, 256, 0, stream>>>(img,  pyr1);
    int t2 = N_B * C_CH * 64 * 32;
    down_kernel<128, 128><<<t2 / 256, 256, 0, stream>>>(pyr1, pyr2);
    int t3 = N_B * C_CH * 32 * 16;
    down_kernel<64, 64><<<t3 / 256, 256, 0, stream>>>(pyr2, pyr3);

    warp_kernel<<<dim3(H_IMG * W_IMG / 256, N_B), 256, 0, stream>>>(
        img, pyr1, pyr2, pyr3, ws_params, out, gridOut);
}